// Round 4
// baseline (222.168 us; speedup 1.0000x reference)
//
#include <hip/hip_runtime.h>
#include <hip/hip_fp16.h>
#include <stdint.h>

#define N_S   4096
#define NTOT  8192
#define D     256
#define NBLK  2080            // 64*65/2 triangular blocks of 128x128

typedef __attribute__((ext_vector_type(8))) short short8v;   // 8 fp16 (4 VGPR)
typedef __attribute__((ext_vector_type(4))) float f32x4;     // MFMA acc

// ---- workspace layout (bytes). Everything rewritten every launch. ----
#define WS_CTR       0                // 2 x uint32 (prep, main last-block ctrs)
#define WS_SQ        4096             // 8192 f32 (32 KB)
#define WS_COLPART   65536            // 128*256 f64 (256 KB)
#define WS_SQPART    327680           // 128 f64
#define WS_COEF      331776           // 1 f32
#define WS_QUAD      335872           // 2080 f64 (signed block partials)
#define WS_XH        524288           // 4 MB fp16, panel/slot-major

// ---------------------------------------------------------------------------
// init: zero the two last-block counters (ws is poisoned 0xAA before timing).
// ---------------------------------------------------------------------------
__global__ void init_kernel(unsigned int* __restrict__ ctr)
{
    if (threadIdx.x == 0) { ctr[0] = 0u; ctr[1] = 0u; }
}

// ---------------------------------------------------------------------------
// prep (+ fused bandwidth tail): one pass over X. Produces
// (a) sq[i] = |x_i|^2 exact fp32, (b) f64 per-block column/sq sums,
// (c) fp16 X in panel/slot-major layout:
//     byte = ((kt*64 + p) << 13) + u*2048 + rp*16 + half*8
// Last block: sum(L2) = 2n*sum(sq) - 2*||sum_i x_i||^2 -> coef[0].
// ---------------------------------------------------------------------------
__global__ __launch_bounds__(256) void prep_kernel(
    const float* __restrict__ src, const float* __restrict__ tgt,
    float* __restrict__ sq, double* __restrict__ colpart,
    double* __restrict__ sqpart, float* __restrict__ coef,
    unsigned int* __restrict__ ctr, char* __restrict__ xh)
{
    const int b    = blockIdx.x;
    const int tid  = threadIdx.x;
    const int w    = tid >> 6;
    const int lane = tid & 63;
    const int row0 = b * 64 + w * 16;
    const float* base = (row0 < N_S) ? (src + (size_t)row0 * D)
                                     : (tgt + (size_t)(row0 - N_S) * D);
    const int kt   = lane >> 3;
    const int u    = (lane >> 1) & 3;
    const int half = lane & 1;

    double ca0 = 0.0, ca1 = 0.0, ca2 = 0.0, ca3 = 0.0;
    double wsq = 0.0;
    for (int r = 0; r < 16; ++r) {
        const int row = row0 + r;
        const float4 v = *(const float4*)(base + (size_t)r * D + lane * 4);
        float s = v.x * v.x + v.y * v.y + v.z * v.z + v.w * v.w;
        ca0 += (double)v.x; ca1 += (double)v.y;
        ca2 += (double)v.z; ca3 += (double)v.w;
        #pragma unroll
        for (int off = 32; off; off >>= 1) s += __shfl_xor(s, off, 64);
        if (lane == 0) sq[row] = s;
        wsq += (double)s;

        const __half h0 = __float2half(v.x), h1 = __float2half(v.y);
        const __half h2 = __float2half(v.z), h3 = __float2half(v.w);
        uint2 q;
        q.x = (uint32_t)(*(const unsigned short*)&h0)
            | ((uint32_t)(*(const unsigned short*)&h1) << 16);
        q.y = (uint32_t)(*(const unsigned short*)&h2)
            | ((uint32_t)(*(const unsigned short*)&h3) << 16);
        const int p  = row >> 7;
        const int rp = row & 127;
        const size_t off_b = (((size_t)(kt * 64 + p)) << 13)
                           + (size_t)u * 2048 + (size_t)rp * 16 + (size_t)half * 8;
        *(uint2*)(xh + off_b) = q;
    }
    __shared__ double cp[4][256];
    __shared__ double sqw[4];
    cp[w][lane * 4 + 0] = ca0;
    cp[w][lane * 4 + 1] = ca1;
    cp[w][lane * 4 + 2] = ca2;
    cp[w][lane * 4 + 3] = ca3;
    if (lane == 0) sqw[w] = wsq;
    __syncthreads();
    colpart[b * 256 + tid] = cp[0][tid] + cp[1][tid] + cp[2][tid] + cp[3][tid];
    if (tid == 0) sqpart[b] = sqw[0] + sqw[1] + sqw[2] + sqw[3];

    // ---- last-block bandwidth tail ----
    __threadfence();
    __shared__ int lastp;
    if (tid == 0) lastp = (atomicAdd(ctr, 1u) == 127u) ? 1 : 0;
    __syncthreads();
    if (!lastp) return;
    __threadfence();
    double cs = 0.0;
    for (int bb = 0; bb < 128; ++bb) cs += colpart[bb * 256 + tid];
    double v  = cs * cs;
    double sv = (tid < 128) ? sqpart[tid] : 0.0;
    #pragma unroll
    for (int off = 32; off; off >>= 1) {
        v  += __shfl_xor(v,  off, 64);
        sv += __shfl_xor(sv, off, 64);
    }
    __shared__ double r2[8];
    if (lane == 0) { r2[w] = v; r2[4 + w] = sv; }
    __syncthreads();
    if (tid == 0) {
        const double s2    = r2[0] + r2[1] + r2[2] + r2[3];
        const double sumsq = r2[4] + r2[5] + r2[6] + r2[7];
        const double n = (double)NTOT;
        const double bwsum = 2.0 * n * sumsq - 2.0 * s2;
        double bandwidth = bwsum / (n * n - n);
        bandwidth *= 0.25;
        coef[0] = (float)(-1.4426950408889634 / (bandwidth * 16.0));
    }
}

// ---------------------------------------------------------------------------
// main (+ fused finalize tail): triangular 128x128 tiles, register-direct
// fp16 MFMA, 4 waves x 64x64. Epilogue y=exp2(-L2*c); sum=y+y^2+y^4+y^8+y^16.
// Block writes SIGNED partial (x2 off-diag) at quad[swz]; last block sums.
// ---------------------------------------------------------------------------
__global__ __launch_bounds__(256) void mmd_main_kernel(
    const char* __restrict__ xh, const float* __restrict__ sq,
    const float* __restrict__ coef, double* __restrict__ quad,
    unsigned int* __restrict__ ctr, float* __restrict__ out)
{
    const int bid = blockIdx.x;
    const int swz = (bid & 7) * 260 + (bid >> 3);   // bijective XCD swizzle
    int by = (int)((129.0 - sqrt((double)(16641 - 8 * swz))) * 0.5);
    if (by < 0) by = 0;
    while ((by + 1) * 64 - ((by + 1) * by) / 2 <= swz) ++by;
    while (by * 64 - (by * (by - 1)) / 2 > swz) --by;
    const int bx = by + (swz - (by * 64 - (by * (by - 1)) / 2));

    const int tid  = threadIdx.x;
    const int w    = tid >> 6;
    const int lane = tid & 63;
    const int wr   = w >> 1, wc = w & 1;
    const int grp  = lane >> 4;
    const int r16  = lane & 15;

    const float negc = coef[0];
    const uint32_t aoff = ((uint32_t)by << 13) + (uint32_t)grp * 2048u
                        + (uint32_t)(wr * 64 + r16) * 16u;
    const uint32_t boff = ((uint32_t)bx << 13) + (uint32_t)grp * 2048u
                        + (uint32_t)(wc * 64 + r16) * 16u;

    f32x4 acc[4][4];
    #pragma unroll
    for (int m = 0; m < 4; ++m)
        #pragma unroll
        for (int n = 0; n < 4; ++n)
            acc[m][n] = (f32x4){0.0f, 0.0f, 0.0f, 0.0f};

    #pragma unroll
    for (int kt = 0; kt < 8; ++kt) {
        short8v a[4], b[4];
        #pragma unroll
        for (int m = 0; m < 4; ++m)
            a[m] = *(const short8v*)(xh + (aoff + (uint32_t)kt * 524288u + (uint32_t)m * 256u));
        #pragma unroll
        for (int n = 0; n < 4; ++n)
            b[n] = *(const short8v*)(xh + (boff + (uint32_t)kt * 524288u + (uint32_t)n * 256u));
        #pragma unroll
        for (int m = 0; m < 4; ++m)
            #pragma unroll
            for (int n = 0; n < 4; ++n)
                acc[m][n] = __builtin_amdgcn_mfma_f32_16x16x32_f16(a[m], b[n], acc[m][n], 0, 0, 0);
    }

    float kst = 0.0f;
    #pragma unroll
    for (int m = 0; m < 4; ++m) {
        float sqa[4];
        #pragma unroll
        for (int r = 0; r < 4; ++r)
            sqa[r] = sq[by * 128 + wr * 64 + m * 16 + grp * 4 + r];
        #pragma unroll
        for (int n = 0; n < 4; ++n) {
            const float sqb = sq[bx * 128 + wc * 64 + n * 16 + r16];
            #pragma unroll
            for (int r = 0; r < 4; ++r) {
                const float l2 = fmaxf(fmaf(-2.0f, acc[m][n][r], sqa[r] + sqb), 0.0f);
                const float y  = __builtin_amdgcn_exp2f(l2 * negc);
                const float y2 = y * y, y4 = y2 * y2, y8 = y4 * y4, y16 = y8 * y8;
                kst += (y + y2) + (y4 + y8) + y16;
            }
        }
    }
    #pragma unroll
    for (int off = 32; off; off >>= 1) kst += __shfl_xor(kst, off, 64);
    __shared__ double wpart[4];
    if (lane == 0) wpart[w] = (double)kst;
    __syncthreads();
    if (tid == 0) {
        const double s = wpart[0] + wpart[1] + wpart[2] + wpart[3];
        const double sgn  = ((by < 32) == (bx < 32)) ? 1.0 : -1.0;
        const double mult = (bx > by) ? 2.0 : 1.0;
        quad[swz] = s * sgn * mult;
    }

    // ---- last-block finalize tail ----
    __threadfence();
    __shared__ int lastm;
    if (tid == 0) lastm = (atomicAdd(ctr, 1u) == (unsigned)(NBLK - 1)) ? 1 : 0;
    __syncthreads();
    if (!lastm) return;
    __threadfence();
    double a = 0.0;
    for (int i = tid; i < NBLK; i += 256) a += quad[i];
    #pragma unroll
    for (int off = 32; off; off >>= 1) a += __shfl_xor(a, off, 64);
    if (lane == 0) wpart[w] = a;
    __syncthreads();
    if (tid == 0) {
        const double tot = wpart[0] + wpart[1] + wpart[2] + wpart[3];
        out[0] = (float)(tot / ((double)N_S * (double)N_S));
    }
}

extern "C" void kernel_launch(void* const* d_in, const int* in_sizes, int n_in,
                              void* d_out, int out_size, void* d_ws, size_t ws_size,
                              hipStream_t stream)
{
    const float* src = (const float*)d_in[0];
    const float* tgt = (const float*)d_in[1];
    float* out = (float*)d_out;
    char*  ws  = (char*)d_ws;

    unsigned int* ctr = (unsigned int*)(ws + WS_CTR);
    float*  sq      = (float*)(ws + WS_SQ);
    double* colpart = (double*)(ws + WS_COLPART);
    double* sqpart  = (double*)(ws + WS_SQPART);
    float*  coef    = (float*)(ws + WS_COEF);
    double* quad    = (double*)(ws + WS_QUAD);
    char*   xh      = ws + WS_XH;

    init_kernel<<<1, 64, 0, stream>>>(ctr);
    prep_kernel<<<128, 256, 0, stream>>>(src, tgt, sq, colpart, sqpart, coef, ctr + 0, xh);
    mmd_main_kernel<<<NBLK, 256, 0, stream>>>(xh, sq, coef, quad, ctr + 1, out);
}

// Round 5
// 86.017 us; speedup vs baseline: 2.5828x; 2.5828x over previous
//
#include <hip/hip_runtime.h>
#include <hip/hip_fp16.h>
#include <stdint.h>

#define N_S   4096
#define NTOT  8192
#define D     256
#define NBLK  2080            // 64*65/2 triangular blocks of 128x128

typedef __attribute__((ext_vector_type(8))) short short8v;   // 8 fp16 (4 VGPR)
typedef __attribute__((ext_vector_type(4))) float f32x4;     // MFMA acc

// ---- workspace layout (bytes). Everything rewritten every launch. ----
#define WS_CTR       0                // 2 x uint32 (prep, main last-block ctrs)
#define WS_ACC       64               // 1 f64 global accumulator
#define WS_SQ        4096             // 8192 f32 (32 KB)
#define WS_COLPART   65536            // 128*256 f64 (256 KB)
#define WS_SQPART    327680           // 128 f64
#define WS_COEF      331776           // 1 f32
#define WS_XH        524288           // 4 MB fp16, panel/slot-major

// ---------------------------------------------------------------------------
// init: zero counters + accumulator (ws is poisoned 0xAA before timing).
// ---------------------------------------------------------------------------
__global__ void init_kernel(unsigned int* __restrict__ ctr,
                            double* __restrict__ accum)
{
    if (threadIdx.x == 0) { ctr[0] = 0u; ctr[1] = 0u; accum[0] = 0.0; }
}

// ---------------------------------------------------------------------------
// prep (+ fused bandwidth tail): one pass over X. Produces
// (a) sq[i] = |x_i|^2 exact fp32, (b) f64 per-block column/sq sums,
// (c) fp16 X in panel/slot-major layout:
//     byte = ((kt*64 + p) << 13) + u*2048 + rp*16 + half*8
// Last block: sum(L2) = 2n*sum(sq) - 2*||sum_i x_i||^2 -> coef[0].
// (threadfence here is 128 streaming blocks -- measured not-hot in R4.)
// ---------------------------------------------------------------------------
__global__ __launch_bounds__(256) void prep_kernel(
    const float* __restrict__ src, const float* __restrict__ tgt,
    float* __restrict__ sq, double* __restrict__ colpart,
    double* __restrict__ sqpart, float* __restrict__ coef,
    unsigned int* __restrict__ ctr, char* __restrict__ xh)
{
    const int b    = blockIdx.x;
    const int tid  = threadIdx.x;
    const int w    = tid >> 6;
    const int lane = tid & 63;
    const int row0 = b * 64 + w * 16;
    const float* base = (row0 < N_S) ? (src + (size_t)row0 * D)
                                     : (tgt + (size_t)(row0 - N_S) * D);
    const int kt   = lane >> 3;
    const int u    = (lane >> 1) & 3;
    const int half = lane & 1;

    double ca0 = 0.0, ca1 = 0.0, ca2 = 0.0, ca3 = 0.0;
    double wsq = 0.0;
    for (int r = 0; r < 16; ++r) {
        const int row = row0 + r;
        const float4 v = *(const float4*)(base + (size_t)r * D + lane * 4);
        float s = v.x * v.x + v.y * v.y + v.z * v.z + v.w * v.w;
        ca0 += (double)v.x; ca1 += (double)v.y;
        ca2 += (double)v.z; ca3 += (double)v.w;
        #pragma unroll
        for (int off = 32; off; off >>= 1) s += __shfl_xor(s, off, 64);
        if (lane == 0) sq[row] = s;
        wsq += (double)s;

        const __half h0 = __float2half(v.x), h1 = __float2half(v.y);
        const __half h2 = __float2half(v.z), h3 = __float2half(v.w);
        uint2 q;
        q.x = (uint32_t)(*(const unsigned short*)&h0)
            | ((uint32_t)(*(const unsigned short*)&h1) << 16);
        q.y = (uint32_t)(*(const unsigned short*)&h2)
            | ((uint32_t)(*(const unsigned short*)&h3) << 16);
        const int p  = row >> 7;
        const int rp = row & 127;
        const size_t off_b = (((size_t)(kt * 64 + p)) << 13)
                           + (size_t)u * 2048 + (size_t)rp * 16 + (size_t)half * 8;
        *(uint2*)(xh + off_b) = q;
    }
    __shared__ double cp[4][256];
    __shared__ double sqw[4];
    cp[w][lane * 4 + 0] = ca0;
    cp[w][lane * 4 + 1] = ca1;
    cp[w][lane * 4 + 2] = ca2;
    cp[w][lane * 4 + 3] = ca3;
    if (lane == 0) sqw[w] = wsq;
    __syncthreads();
    colpart[b * 256 + tid] = cp[0][tid] + cp[1][tid] + cp[2][tid] + cp[3][tid];
    if (tid == 0) sqpart[b] = sqw[0] + sqw[1] + sqw[2] + sqw[3];

    // ---- last-block bandwidth tail ----
    __threadfence();
    __shared__ int lastp;
    if (tid == 0) lastp = (atomicAdd(ctr, 1u) == 127u) ? 1 : 0;
    __syncthreads();
    if (!lastp) return;
    __threadfence();
    double cs = 0.0;
    for (int bb = 0; bb < 128; ++bb) cs += colpart[bb * 256 + tid];
    double v  = cs * cs;
    double sv = (tid < 128) ? sqpart[tid] : 0.0;
    #pragma unroll
    for (int off = 32; off; off >>= 1) {
        v  += __shfl_xor(v,  off, 64);
        sv += __shfl_xor(sv, off, 64);
    }
    __shared__ double r2[8];
    if (lane == 0) { r2[w] = v; r2[4 + w] = sv; }
    __syncthreads();
    if (tid == 0) {
        const double s2    = r2[0] + r2[1] + r2[2] + r2[3];
        const double sumsq = r2[4] + r2[5] + r2[6] + r2[7];
        const double n = (double)NTOT;
        const double bwsum = 2.0 * n * sumsq - 2.0 * s2;
        double bandwidth = bwsum / (n * n - n);
        bandwidth *= 0.25;
        coef[0] = (float)(-1.4426950408889634 / (bandwidth * 16.0));
    }
}

// ---------------------------------------------------------------------------
// main (+ fence-free finalize tail): triangular 128x128 tiles, register-
// direct fp16 MFMA, 4 waves x 64x64. Epilogue y=exp2(-L2*c);
// sum = y+y^2+y^4+y^8+y^16.
// Tail: relaxed agent-scope f64 atomicAdd into accum (performed at L3, no
// cache ops -> no L2 invalidation), s_waitcnt vmcnt(0) to order completion,
// then relaxed counter RMW. Last block re-reads accum via atomicAdd(+0.0)
// (same-address RMW total order => sees all 2080 contributions).
// ---------------------------------------------------------------------------
__global__ __launch_bounds__(256) void mmd_main_kernel(
    const char* __restrict__ xh, const float* __restrict__ sq,
    const float* __restrict__ coef, double* __restrict__ accum,
    unsigned int* __restrict__ ctr, float* __restrict__ out)
{
    const int bid = blockIdx.x;
    const int swz = (bid & 7) * 260 + (bid >> 3);   // bijective XCD swizzle
    int by = (int)((129.0 - sqrt((double)(16641 - 8 * swz))) * 0.5);
    if (by < 0) by = 0;
    while ((by + 1) * 64 - ((by + 1) * by) / 2 <= swz) ++by;
    while (by * 64 - (by * (by - 1)) / 2 > swz) --by;
    const int bx = by + (swz - (by * 64 - (by * (by - 1)) / 2));

    const int tid  = threadIdx.x;
    const int w    = tid >> 6;
    const int lane = tid & 63;
    const int wr   = w >> 1, wc = w & 1;
    const int grp  = lane >> 4;
    const int r16  = lane & 15;

    const float negc = coef[0];
    const uint32_t aoff = ((uint32_t)by << 13) + (uint32_t)grp * 2048u
                        + (uint32_t)(wr * 64 + r16) * 16u;
    const uint32_t boff = ((uint32_t)bx << 13) + (uint32_t)grp * 2048u
                        + (uint32_t)(wc * 64 + r16) * 16u;

    f32x4 acc[4][4];
    #pragma unroll
    for (int m = 0; m < 4; ++m)
        #pragma unroll
        for (int n = 0; n < 4; ++n)
            acc[m][n] = (f32x4){0.0f, 0.0f, 0.0f, 0.0f};

    #pragma unroll
    for (int kt = 0; kt < 8; ++kt) {
        short8v a[4], b[4];
        #pragma unroll
        for (int m = 0; m < 4; ++m)
            a[m] = *(const short8v*)(xh + (aoff + (uint32_t)kt * 524288u + (uint32_t)m * 256u));
        #pragma unroll
        for (int n = 0; n < 4; ++n)
            b[n] = *(const short8v*)(xh + (boff + (uint32_t)kt * 524288u + (uint32_t)n * 256u));
        #pragma unroll
        for (int m = 0; m < 4; ++m)
            #pragma unroll
            for (int n = 0; n < 4; ++n)
                acc[m][n] = __builtin_amdgcn_mfma_f32_16x16x32_f16(a[m], b[n], acc[m][n], 0, 0, 0);
    }

    // epilogue. C layout: col = lane&15 (B/n side), row = grp*4 + reg (A/m side)
    float kst = 0.0f;
    #pragma unroll
    for (int m = 0; m < 4; ++m) {
        float sqa[4];
        #pragma unroll
        for (int r = 0; r < 4; ++r)
            sqa[r] = sq[by * 128 + wr * 64 + m * 16 + grp * 4 + r];
        #pragma unroll
        for (int n = 0; n < 4; ++n) {
            const float sqb = sq[bx * 128 + wc * 64 + n * 16 + r16];
            #pragma unroll
            for (int r = 0; r < 4; ++r) {
                const float l2 = fmaxf(fmaf(-2.0f, acc[m][n][r], sqa[r] + sqb), 0.0f);
                const float y  = __builtin_amdgcn_exp2f(l2 * negc);
                const float y2 = y * y, y4 = y2 * y2, y8 = y4 * y4, y16 = y8 * y8;
                kst += (y + y2) + (y4 + y8) + y16;
            }
        }
    }
    #pragma unroll
    for (int off = 32; off; off >>= 1) kst += __shfl_xor(kst, off, 64);
    __shared__ double wpart[4];
    if (lane == 0) wpart[w] = (double)kst;
    __syncthreads();

    if (tid == 0) {
        const double s = wpart[0] + wpart[1] + wpart[2] + wpart[3];
        const double sgn  = ((by < 32) == (bx < 32)) ? 1.0 : -1.0;
        const double mult = (bx > by) ? 2.0 : 1.0;
        const double part = s * sgn * mult;

        // relaxed agent-scope f64 add at the coherent point (no cache ops)
        double old = __hip_atomic_fetch_add(accum, part,
                        __ATOMIC_RELAXED, __HIP_MEMORY_SCOPE_AGENT);
        // order: accum RMW must be complete before the counter RMW issues
        asm volatile("s_waitcnt vmcnt(0)" :: "v"(old) : "memory");
        const unsigned c = __hip_atomic_fetch_add(ctr, 1u,
                        __ATOMIC_RELAXED, __HIP_MEMORY_SCOPE_AGENT);
        if (c == (unsigned)(NBLK - 1)) {
            const double tot = __hip_atomic_fetch_add(accum, 0.0,
                        __ATOMIC_RELAXED, __HIP_MEMORY_SCOPE_AGENT);
            out[0] = (float)(tot / ((double)N_S * (double)N_S));
        }
    }
}

extern "C" void kernel_launch(void* const* d_in, const int* in_sizes, int n_in,
                              void* d_out, int out_size, void* d_ws, size_t ws_size,
                              hipStream_t stream)
{
    const float* src = (const float*)d_in[0];
    const float* tgt = (const float*)d_in[1];
    float* out = (float*)d_out;
    char*  ws  = (char*)d_ws;

    unsigned int* ctr = (unsigned int*)(ws + WS_CTR);
    double* accum   = (double*)(ws + WS_ACC);
    float*  sq      = (float*)(ws + WS_SQ);
    double* colpart = (double*)(ws + WS_COLPART);
    double* sqpart  = (double*)(ws + WS_SQPART);
    float*  coef    = (float*)(ws + WS_COEF);
    char*   xh      = ws + WS_XH;

    init_kernel<<<1, 64, 0, stream>>>(ctr, accum);
    prep_kernel<<<128, 256, 0, stream>>>(src, tgt, sq, colpart, sqpart, coef, ctr + 0, xh);
    mmd_main_kernel<<<NBLK, 256, 0, stream>>>(xh, sq, coef, accum, ctr + 1, out);
}

// Round 6
// 55.869 us; speedup vs baseline: 3.9766x; 1.5396x over previous
//
#include <hip/hip_runtime.h>
#include <hip/hip_fp16.h>
#include <stdint.h>

#define N_S   4096
#define NTOT  8192
#define D     256
#define NBLK  2080            // 64*65/2 triangular blocks of 128x128

typedef __attribute__((ext_vector_type(8))) short short8v;   // 8 fp16 (4 VGPR)
typedef __attribute__((ext_vector_type(4))) float f32x4;     // MFMA acc

// ---- workspace layout (bytes). Everything rewritten every launch. ----
#define WS_CTR       0                // u32 prep last-block counter
#define WS_SQTOT     64               // f64 sum of |x_i|^2
#define WS_COLSUM    128              // 256 f64 column sums (2 KB)
#define WS_ACC       2560             // 128 f64 partial-sum slots (1 KB)
#define WS_SQ        4096             // 8192 f32 (32 KB)
#define WS_COEF      36864            // 1 f32
#define WS_XH        65536            // 4 MB fp16, panel/slot-major

// ---------------------------------------------------------------------------
// init: zero counters/accumulators (ws is poisoned 0xAA before timing).
// ---------------------------------------------------------------------------
__global__ __launch_bounds__(256) void init_kernel(char* __restrict__ ws)
{
    const int tid = threadIdx.x;
    ((double*)(ws + WS_COLSUM))[tid] = 0.0;
    if (tid < 128) ((double*)(ws + WS_ACC))[tid] = 0.0;
    if (tid == 0) {
        *(unsigned int*)(ws + WS_CTR) = 0u;
        *(double*)(ws + WS_SQTOT)     = 0.0;
    }
}

// ---------------------------------------------------------------------------
// prep (+ fused bandwidth tail, fence-free): one pass over X. Produces
// (a) sq[i] = |x_i|^2 exact fp32, (b) atomic f64 column sums + sq total,
// (c) fp16 X in panel/slot-major layout:
//     byte = ((kt*64 + p) << 13) + u*2048 + rp*16 + half*8
// Ordering protocol (no cache ops): returned-value atomicAdd -> per-thread
// s_waitcnt vmcnt(0) -> __syncthreads -> ctr RMW. Last block reads the
// atomically-written sums with relaxed agent-scope atomic loads.
// ---------------------------------------------------------------------------
__global__ __launch_bounds__(256) void prep_kernel(
    const float* __restrict__ src, const float* __restrict__ tgt,
    float* __restrict__ sq, double* __restrict__ colsum,
    double* __restrict__ sqtot, float* __restrict__ coef,
    unsigned int* __restrict__ ctr, char* __restrict__ xh)
{
    const int b    = blockIdx.x;
    const int tid  = threadIdx.x;
    const int w    = tid >> 6;
    const int lane = tid & 63;
    const int row0 = b * 64 + w * 16;
    const float* base = (row0 < N_S) ? (src + (size_t)row0 * D)
                                     : (tgt + (size_t)(row0 - N_S) * D);
    const int kt   = lane >> 3;
    const int u    = (lane >> 1) & 3;
    const int half = lane & 1;

    double ca0 = 0.0, ca1 = 0.0, ca2 = 0.0, ca3 = 0.0;
    double wsq = 0.0;
    for (int r = 0; r < 16; ++r) {
        const int row = row0 + r;
        const float4 v = *(const float4*)(base + (size_t)r * D + lane * 4);
        float s = v.x * v.x + v.y * v.y + v.z * v.z + v.w * v.w;
        ca0 += (double)v.x; ca1 += (double)v.y;
        ca2 += (double)v.z; ca3 += (double)v.w;
        #pragma unroll
        for (int off = 32; off; off >>= 1) s += __shfl_xor(s, off, 64);
        if (lane == 0) sq[row] = s;
        wsq += (double)s;

        const __half h0 = __float2half(v.x), h1 = __float2half(v.y);
        const __half h2 = __float2half(v.z), h3 = __float2half(v.w);
        uint2 q;
        q.x = (uint32_t)(*(const unsigned short*)&h0)
            | ((uint32_t)(*(const unsigned short*)&h1) << 16);
        q.y = (uint32_t)(*(const unsigned short*)&h2)
            | ((uint32_t)(*(const unsigned short*)&h3) << 16);
        const int p  = row >> 7;
        const int rp = row & 127;
        const size_t off_b = (((size_t)(kt * 64 + p)) << 13)
                           + (size_t)u * 2048 + (size_t)rp * 16 + (size_t)half * 8;
        *(uint2*)(xh + off_b) = q;
    }
    __shared__ double cp[4][256];
    __shared__ double sqw[4];
    cp[w][lane * 4 + 0] = ca0;
    cp[w][lane * 4 + 1] = ca1;
    cp[w][lane * 4 + 2] = ca2;
    cp[w][lane * 4 + 3] = ca3;
    if (lane == 0) sqw[w] = wsq;
    __syncthreads();

    const double cpv = cp[0][tid] + cp[1][tid] + cp[2][tid] + cp[3][tid];
    double old0 = __hip_atomic_fetch_add(&colsum[tid], cpv,
                      __ATOMIC_RELAXED, __HIP_MEMORY_SCOPE_AGENT);
    double old1 = 0.0;
    if (tid == 0)
        old1 = __hip_atomic_fetch_add(sqtot, sqw[0] + sqw[1] + sqw[2] + sqw[3],
                      __ATOMIC_RELAXED, __HIP_MEMORY_SCOPE_AGENT);
    asm volatile("" :: "v"(old0), "v"(old1));          // keep results live
    asm volatile("s_waitcnt vmcnt(0)" ::: "memory");   // our RMWs are ack'd
    __syncthreads();

    __shared__ int lastp;
    if (tid == 0)
        lastp = (__hip_atomic_fetch_add(ctr, 1u,
                   __ATOMIC_RELAXED, __HIP_MEMORY_SCOPE_AGENT) == 127u) ? 1 : 0;
    __syncthreads();
    if (!lastp) return;

    const double cs = __hip_atomic_load(&colsum[tid],
                          __ATOMIC_RELAXED, __HIP_MEMORY_SCOPE_AGENT);
    double v = cs * cs;
    #pragma unroll
    for (int off = 32; off; off >>= 1) v += __shfl_xor(v, off, 64);
    __shared__ double r2[4];
    if (lane == 0) r2[w] = v;
    __syncthreads();
    if (tid == 0) {
        const double s2    = r2[0] + r2[1] + r2[2] + r2[3];   // ||sum_i x_i||^2
        const double sumsq = __hip_atomic_load(sqtot,
                                 __ATOMIC_RELAXED, __HIP_MEMORY_SCOPE_AGENT);
        const double n = (double)NTOT;
        const double bwsum = 2.0 * n * sumsq - 2.0 * s2;      // sum_ij L2_ij
        double bandwidth = bwsum / (n * n - n);
        bandwidth *= 0.25;                                    // / 2^(5//2)
        coef[0] = (float)(-1.4426950408889634 / (bandwidth * 16.0));
    }
}

// ---------------------------------------------------------------------------
// main: triangular 128x128 tiles, register-direct fp16 MFMA with an explicit
// 2-stage prefetch (loads for kt+1 issued before kt's MFMAs). 4 waves x 64x64.
// Epilogue y=exp2(-L2*c); sum = y+y^2+y^4+y^8+y^16. One relaxed f64 atomicAdd
// per block into accum[bid&127] (no ctr, no waits, no convoy).
// ---------------------------------------------------------------------------
__global__ __launch_bounds__(256) void mmd_main_kernel(
    const char* __restrict__ xh, const float* __restrict__ sq,
    const float* __restrict__ coef, double* __restrict__ accum)
{
    const int bid = blockIdx.x;
    const int swz = (bid & 7) * 260 + (bid >> 3);   // bijective XCD swizzle
    int by = (int)((129.0 - sqrt((double)(16641 - 8 * swz))) * 0.5);
    if (by < 0) by = 0;
    while ((by + 1) * 64 - ((by + 1) * by) / 2 <= swz) ++by;
    while (by * 64 - (by * (by - 1)) / 2 > swz) --by;
    const int bx = by + (swz - (by * 64 - (by * (by - 1)) / 2));

    const int tid  = threadIdx.x;
    const int w    = tid >> 6;
    const int lane = tid & 63;
    const int wr   = w >> 1, wc = w & 1;
    const int grp  = lane >> 4;
    const int r16  = lane & 15;

    const float negc = coef[0];
    const uint32_t aoff = ((uint32_t)by << 13) + (uint32_t)grp * 2048u
                        + (uint32_t)(wr * 64 + r16) * 16u;
    const uint32_t boff = ((uint32_t)bx << 13) + (uint32_t)grp * 2048u
                        + (uint32_t)(wc * 64 + r16) * 16u;

    f32x4 acc[4][4];
    #pragma unroll
    for (int m = 0; m < 4; ++m)
        #pragma unroll
        for (int n = 0; n < 4; ++n)
            acc[m][n] = (f32x4){0.0f, 0.0f, 0.0f, 0.0f};

#define LOADK(KT, A, B)                                                        \
    do {                                                                       \
        const uint32_t kb_ = (uint32_t)(KT) * 524288u;                         \
        _Pragma("unroll")                                                      \
        for (int i_ = 0; i_ < 4; ++i_)                                         \
            A[i_] = *(const short8v*)(xh + (aoff + kb_ + (uint32_t)i_ * 256u));\
        _Pragma("unroll")                                                      \
        for (int i_ = 0; i_ < 4; ++i_)                                         \
            B[i_] = *(const short8v*)(xh + (boff + kb_ + (uint32_t)i_ * 256u));\
    } while (0)

    short8v aC[4], bC[4], aN[4], bN[4];
    LOADK(0, aC, bC);
    #pragma unroll
    for (int kt = 0; kt < 8; ++kt) {
        if (kt < 7) LOADK(kt + 1, aN, bN);      // prefetch next k-tile
        #pragma unroll
        for (int m = 0; m < 4; ++m)
            #pragma unroll
            for (int n = 0; n < 4; ++n)
                acc[m][n] = __builtin_amdgcn_mfma_f32_16x16x32_f16(aC[m], bC[n], acc[m][n], 0, 0, 0);
        if (kt < 7) {
            #pragma unroll
            for (int i = 0; i < 4; ++i) { aC[i] = aN[i]; bC[i] = bN[i]; }
        }
    }
#undef LOADK

    // epilogue. C layout: col = lane&15 (B/n side), row = grp*4 + reg (A/m side)
    float kst = 0.0f;
    #pragma unroll
    for (int m = 0; m < 4; ++m) {
        float sqa[4];
        #pragma unroll
        for (int r = 0; r < 4; ++r)
            sqa[r] = sq[by * 128 + wr * 64 + m * 16 + grp * 4 + r];
        #pragma unroll
        for (int n = 0; n < 4; ++n) {
            const float sqb = sq[bx * 128 + wc * 64 + n * 16 + r16];
            #pragma unroll
            for (int r = 0; r < 4; ++r) {
                const float l2 = fmaxf(fmaf(-2.0f, acc[m][n][r], sqa[r] + sqb), 0.0f);
                const float y  = __builtin_amdgcn_exp2f(l2 * negc);
                const float y2 = y * y, y4 = y2 * y2, y8 = y4 * y4, y16 = y8 * y8;
                kst += (y + y2) + (y4 + y8) + y16;
            }
        }
    }
    #pragma unroll
    for (int off = 32; off; off >>= 1) kst += __shfl_xor(kst, off, 64);
    __shared__ double wpart[4];
    if (lane == 0) wpart[w] = (double)kst;
    __syncthreads();
    if (tid == 0) {
        const double s = wpart[0] + wpart[1] + wpart[2] + wpart[3];
        const double sgn  = ((by < 32) == (bx < 32)) ? 1.0 : -1.0;
        const double mult = (bx > by) ? 2.0 : 1.0;
        __hip_atomic_fetch_add(&accum[bid & 127], s * sgn * mult,
                               __ATOMIC_RELAXED, __HIP_MEMORY_SCOPE_AGENT);
    }
}

// ---------------------------------------------------------------------------
// finalize: one wave sums the 128 accumulator slots -> scalar output.
// ---------------------------------------------------------------------------
__global__ __launch_bounds__(64) void finalize_kernel(
    const double* __restrict__ accum, float* __restrict__ out)
{
    const int lane = threadIdx.x;
    double a = accum[lane] + accum[lane + 64];
    #pragma unroll
    for (int off = 32; off; off >>= 1) a += __shfl_xor(a, off, 64);
    if (lane == 0)
        out[0] = (float)(a / ((double)N_S * (double)N_S));
}

extern "C" void kernel_launch(void* const* d_in, const int* in_sizes, int n_in,
                              void* d_out, int out_size, void* d_ws, size_t ws_size,
                              hipStream_t stream)
{
    const float* src = (const float*)d_in[0];
    const float* tgt = (const float*)d_in[1];
    float* out = (float*)d_out;
    char*  ws  = (char*)d_ws;

    unsigned int* ctr = (unsigned int*)(ws + WS_CTR);
    double* sqtot   = (double*)(ws + WS_SQTOT);
    double* colsum  = (double*)(ws + WS_COLSUM);
    double* accum   = (double*)(ws + WS_ACC);
    float*  sq      = (float*)(ws + WS_SQ);
    float*  coef    = (float*)(ws + WS_COEF);
    char*   xh      = ws + WS_XH;

    init_kernel<<<1, 256, 0, stream>>>(ws);
    prep_kernel<<<128, 256, 0, stream>>>(src, tgt, sq, colsum, sqtot, coef, ctr, xh);
    mmd_main_kernel<<<NBLK, 256, 0, stream>>>(xh, sq, coef, accum);
    finalize_kernel<<<1, 64, 0, stream>>>(accum, out);
}

// Round 7
// 47.688 us; speedup vs baseline: 4.6588x; 1.1715x over previous
//
#include <hip/hip_runtime.h>
#include <stdint.h>

#define N_S   4096
#define NTOT  8192
#define D     256
#define NBLK  2080            // 64*65/2 triangular blocks of 128x128
#define PREPB 256             // prep blocks (32 rows each)

typedef __attribute__((ext_vector_type(4))) float f32x4;     // MFMA acc
typedef __attribute__((ext_vector_type(2))) long longx2;     // 16B = 2 fp8 frags

// ---- workspace layout (bytes). Everything rewritten every launch. ----
#define WS_CTR       0                // u32 prep last-block counter
#define WS_SQTOT     64               // f64 sum of |x_i|^2
#define WS_COLSUM    128              // 256 f64 column sums (2 KB)
#define WS_ACC       2560             // 128 f64 partial-sum slots (1 KB)
#define WS_SQ        4096             // 8192 f32 (32 KB)
#define WS_COEF      36864            // 1 f32
#define WS_XH        65536            // 2 MB fp8, panel/kt-pair/slot-major

// fp8 layout: for row R (panel p=R>>7, rp=R&127), col c (kt=c>>5, u=(c>>3)&3,
// j=c&7):  byte = (p<<15) + ((kt>>1)<<13) + u*2048 + rp*16 + (kt&1)*8 + j
// => a lane's 16B granule at (pair,u,rp) = [kt even 8B | kt odd 8B].

// ---------------------------------------------------------------------------
__global__ __launch_bounds__(256) void init_kernel(char* __restrict__ ws)
{
    const int tid = threadIdx.x;
    ((double*)(ws + WS_COLSUM))[tid] = 0.0;
    if (tid < 128) ((double*)(ws + WS_ACC))[tid] = 0.0;
    if (tid == 0) {
        *(unsigned int*)(ws + WS_CTR) = 0u;
        *(double*)(ws + WS_SQTOT)     = 0.0;
    }
}

// ---------------------------------------------------------------------------
// prep (+ fused bandwidth tail, fence-free): one pass over X. Produces
// (a) sq[i] = |x_i|^2 exact fp32, (b) atomic f64 column sums + sq total,
// (c) fp8 e4m3 X in the kt-pair layout above.
// 256 blocks x 256 threads; wave handles 8 rows; lane owns 4 columns.
// ---------------------------------------------------------------------------
__global__ __launch_bounds__(256) void prep_kernel(
    const float* __restrict__ src, const float* __restrict__ tgt,
    float* __restrict__ sq, double* __restrict__ colsum,
    double* __restrict__ sqtot, float* __restrict__ coef,
    unsigned int* __restrict__ ctr, char* __restrict__ xh)
{
    const int b    = blockIdx.x;
    const int tid  = threadIdx.x;
    const int w    = tid >> 6;
    const int lane = tid & 63;
    const int row0 = b * 32 + w * 8;
    const float* base = (row0 < N_S) ? (src + (size_t)row0 * D)
                                     : (tgt + (size_t)(row0 - N_S) * D);
    const int kt = lane >> 3;            // col k-tile of this lane's 4 cols
    const int u  = (lane >> 1) & 3;      // 8-elem k-slot
    const int qb = (lane & 1) * 4;       // dword within the 8B half-granule
    const uint32_t sub = (((uint32_t)kt >> 1) << 13) + (uint32_t)u * 2048u
                       + ((uint32_t)kt & 1u) * 8u + (uint32_t)qb;

    double ca0 = 0.0, ca1 = 0.0, ca2 = 0.0, ca3 = 0.0;
    double wsq = 0.0;
    for (int r = 0; r < 8; ++r) {
        const int row = row0 + r;
        const float4 v = *(const float4*)(base + (size_t)r * D + lane * 4);
        float s = v.x * v.x + v.y * v.y + v.z * v.z + v.w * v.w;
        ca0 += (double)v.x; ca1 += (double)v.y;
        ca2 += (double)v.z; ca3 += (double)v.w;
        #pragma unroll
        for (int off = 32; off; off >>= 1) s += __shfl_xor(s, off, 64);
        if (lane == 0) sq[row] = s;
        wsq += (double)s;

        int pk = __builtin_amdgcn_cvt_pk_fp8_f32(v.x, v.y, 0, false);
        pk     = __builtin_amdgcn_cvt_pk_fp8_f32(v.z, v.w, pk, true);
        const uint32_t off_b = ((uint32_t)(row >> 7) << 15)
                             + (uint32_t)(row & 127) * 16u + sub;
        *(int*)(xh + off_b) = pk;
    }
    __shared__ double cp[4][256];
    __shared__ double sqw[4];
    cp[w][lane * 4 + 0] = ca0;
    cp[w][lane * 4 + 1] = ca1;
    cp[w][lane * 4 + 2] = ca2;
    cp[w][lane * 4 + 3] = ca3;
    if (lane == 0) sqw[w] = wsq;
    __syncthreads();

    const double cpv = cp[0][tid] + cp[1][tid] + cp[2][tid] + cp[3][tid];
    double old0 = __hip_atomic_fetch_add(&colsum[tid], cpv,
                      __ATOMIC_RELAXED, __HIP_MEMORY_SCOPE_AGENT);
    double old1 = 0.0;
    if (tid == 0)
        old1 = __hip_atomic_fetch_add(sqtot, sqw[0] + sqw[1] + sqw[2] + sqw[3],
                      __ATOMIC_RELAXED, __HIP_MEMORY_SCOPE_AGENT);
    asm volatile("" :: "v"(old0), "v"(old1));          // keep results live
    asm volatile("s_waitcnt vmcnt(0)" ::: "memory");   // our RMWs are ack'd
    __syncthreads();

    __shared__ int lastp;
    if (tid == 0)
        lastp = (__hip_atomic_fetch_add(ctr, 1u,
                   __ATOMIC_RELAXED, __HIP_MEMORY_SCOPE_AGENT)
                 == (unsigned)(PREPB - 1)) ? 1 : 0;
    __syncthreads();
    if (!lastp) return;

    const double cs = __hip_atomic_load(&colsum[tid],
                          __ATOMIC_RELAXED, __HIP_MEMORY_SCOPE_AGENT);
    double v = cs * cs;
    #pragma unroll
    for (int off = 32; off; off >>= 1) v += __shfl_xor(v, off, 64);
    __shared__ double r2[4];
    if (lane == 0) r2[w] = v;
    __syncthreads();
    if (tid == 0) {
        const double s2    = r2[0] + r2[1] + r2[2] + r2[3];   // ||sum_i x_i||^2
        const double sumsq = __hip_atomic_load(sqtot,
                                 __ATOMIC_RELAXED, __HIP_MEMORY_SCOPE_AGENT);
        const double n = (double)NTOT;
        const double bwsum = 2.0 * n * sumsq - 2.0 * s2;      // sum_ij L2_ij
        double bandwidth = bwsum / (n * n - n);
        bandwidth *= 0.25;                                    // / 2^(5//2)
        coef[0] = (float)(-1.4426950408889634 / (bandwidth * 16.0));
    }
}

// ---------------------------------------------------------------------------
// main: triangular 128x128 tiles, register-direct fp8 MFMA; 16B loads carry
// two k-tiles (kt-pair layout), prefetch depth = 1 pair. 4 waves x 64x64.
// Epilogue y=exp2(negc*L2); sum = y+y^2+y^4+y^8+y^16; exact 5.0 on the true
// diagonal (fp8 dot bias fix). One relaxed f64 atomicAdd into accum[bid&127].
// ---------------------------------------------------------------------------
__global__ __launch_bounds__(256) void mmd_main_kernel(
    const char* __restrict__ xh, const float* __restrict__ sq,
    const float* __restrict__ coef, double* __restrict__ accum)
{
    const int bid = blockIdx.x;
    const int swz = (bid & 7) * 260 + (bid >> 3);   // bijective XCD swizzle
    int by = (int)((129.0 - sqrt((double)(16641 - 8 * swz))) * 0.5);
    if (by < 0) by = 0;
    while ((by + 1) * 64 - ((by + 1) * by) / 2 <= swz) ++by;
    while (by * 64 - (by * (by - 1)) / 2 > swz) --by;
    const int bx = by + (swz - (by * 64 - (by * (by - 1)) / 2));

    const int tid  = threadIdx.x;
    const int w    = tid >> 6;
    const int lane = tid & 63;
    const int wr   = w >> 1, wc = w & 1;
    const int grp  = lane >> 4;
    const int r16  = lane & 15;

    const float negc = coef[0];
    const uint32_t aoff = ((uint32_t)by << 15) + (uint32_t)grp * 2048u
                        + (uint32_t)(wr * 64 + r16) * 16u;
    const uint32_t boff = ((uint32_t)bx << 15) + (uint32_t)grp * 2048u
                        + (uint32_t)(wc * 64 + r16) * 16u;

    f32x4 acc[4][4];
    #pragma unroll
    for (int m = 0; m < 4; ++m)
        #pragma unroll
        for (int n = 0; n < 4; ++n)
            acc[m][n] = (f32x4){0.0f, 0.0f, 0.0f, 0.0f};

#define LOADP(PR, A, B)                                                        \
    do {                                                                       \
        const uint32_t kb_ = (uint32_t)(PR) * 8192u;                           \
        _Pragma("unroll")                                                      \
        for (int i_ = 0; i_ < 4; ++i_)                                         \
            A[i_] = *(const longx2*)(xh + (aoff + kb_ + (uint32_t)i_ * 256u)); \
        _Pragma("unroll")                                                      \
        for (int i_ = 0; i_ < 4; ++i_)                                         \
            B[i_] = *(const longx2*)(xh + (boff + kb_ + (uint32_t)i_ * 256u)); \
    } while (0)

    longx2 aC[4], bC[4], aN[4], bN[4];
    LOADP(0, aC, bC);
    #pragma unroll
    for (int pr = 0; pr < 4; ++pr) {                 // 4 kt-pairs = K 256
        if (pr < 3) LOADP(pr + 1, aN, bN);           // prefetch next pair
        #pragma unroll
        for (int m = 0; m < 4; ++m)
            #pragma unroll
            for (int n = 0; n < 4; ++n) {
                acc[m][n] = __builtin_amdgcn_mfma_f32_16x16x32_fp8_fp8(
                                aC[m].x, bC[n].x, acc[m][n], 0, 0, 0);
                acc[m][n] = __builtin_amdgcn_mfma_f32_16x16x32_fp8_fp8(
                                aC[m].y, bC[n].y, acc[m][n], 0, 0, 0);
            }
        if (pr < 3) {
            #pragma unroll
            for (int i = 0; i < 4; ++i) { aC[i] = aN[i]; bC[i] = bN[i]; }
        }
    }
#undef LOADP

    // epilogue. C layout: col = lane&15 (B/n side), row = grp*4 + reg (A/m side)
    const float m2c = -2.0f * negc;
    float kst = 0.0f;
    #pragma unroll
    for (int m = 0; m < 4; ++m) {
        float pas[4];
        #pragma unroll
        for (int r = 0; r < 4; ++r)
            pas[r] = negc * sq[by * 128 + wr * 64 + m * 16 + grp * 4 + r];
        #pragma unroll
        for (int n = 0; n < 4; ++n) {
            const float pb = negc * sq[bx * 128 + wc * 64 + n * 16 + r16];
            #pragma unroll
            for (int r = 0; r < 4; ++r) {
                const float arg = fmaf(m2c, acc[m][n][r], pas[r] + pb);
                const float y  = __builtin_amdgcn_exp2f(arg);
                const float y2 = y * y, y4 = y2 * y2, y8 = y4 * y4, y16 = y8 * y8;
                kst += (y + y2) + (y4 + y8) + y16;
            }
        }
    }
    // diagonal fix-up: true diag has L2=0 -> kernel sum exactly 5. Only waves
    // on the tile diagonal of diagonal blocks hold diag elements:
    // col(m,r16) == row(m,grp*4+rr) requires r16>>2==grp, rr=r16&3, n==m.
    if (bx == by && wr == wc && (r16 >> 2) == grp) {
        const int rr = r16 & 3;
        #pragma unroll
        for (int m = 0; m < 4; ++m) {
            const float sqv = sq[by * 128 + wr * 64 + m * 16 + r16];
            const float arg = fmaf(m2c, acc[m][m][rr], 2.0f * negc * sqv);
            const float y  = __builtin_amdgcn_exp2f(arg);
            const float y2 = y * y, y4 = y2 * y2, y8 = y4 * y4, y16 = y8 * y8;
            kst += 5.0f - ((y + y2) + (y4 + y8) + y16);
        }
    }
    #pragma unroll
    for (int off = 32; off; off >>= 1) kst += __shfl_xor(kst, off, 64);
    __shared__ double wpart[4];
    if (lane == 0) wpart[w] = (double)kst;
    __syncthreads();
    if (tid == 0) {
        const double s = wpart[0] + wpart[1] + wpart[2] + wpart[3];
        const double sgn  = ((by < 32) == (bx < 32)) ? 1.0 : -1.0;
        const double mult = (bx > by) ? 2.0 : 1.0;
        __hip_atomic_fetch_add(&accum[bid & 127], s * sgn * mult,
                               __ATOMIC_RELAXED, __HIP_MEMORY_SCOPE_AGENT);
    }
}

// ---------------------------------------------------------------------------
// finalize: one wave sums the 128 accumulator slots -> scalar output.
// ---------------------------------------------------------------------------
__global__ __launch_bounds__(64) void finalize_kernel(
    const double* __restrict__ accum, float* __restrict__ out)
{
    const int lane = threadIdx.x;
    double a = accum[lane] + accum[lane + 64];
    #pragma unroll
    for (int off = 32; off; off >>= 1) a += __shfl_xor(a, off, 64);
    if (lane == 0)
        out[0] = (float)(a / ((double)N_S * (double)N_S));
}

extern "C" void kernel_launch(void* const* d_in, const int* in_sizes, int n_in,
                              void* d_out, int out_size, void* d_ws, size_t ws_size,
                              hipStream_t stream)
{
    const float* src = (const float*)d_in[0];
    const float* tgt = (const float*)d_in[1];
    float* out = (float*)d_out;
    char*  ws  = (char*)d_ws;

    unsigned int* ctr = (unsigned int*)(ws + WS_CTR);
    double* sqtot   = (double*)(ws + WS_SQTOT);
    double* colsum  = (double*)(ws + WS_COLSUM);
    double* accum   = (double*)(ws + WS_ACC);
    float*  sq      = (float*)(ws + WS_SQ);
    float*  coef    = (float*)(ws + WS_COEF);
    char*   xh      = ws + WS_XH;

    init_kernel<<<1, 256, 0, stream>>>(ws);
    prep_kernel<<<PREPB, 256, 0, stream>>>(src, tgt, sq, colsum, sqtot, coef, ctr, xh);
    mmd_main_kernel<<<NBLK, 256, 0, stream>>>(xh, sq, coef, accum);
    finalize_kernel<<<1, 64, 0, stream>>>(accum, out);
}